// Round 5
// baseline (272.058 us; speedup 1.0000x reference)
//
#include <hip/hip_runtime.h>
#include <stdint.h>

#define BB 64
#define NN 4096
#define DD 64
#define NSL 7
#define HH 128
#define NITER 3
#define TPT 2   // tiles (of 64 rows) per block in ln_kv

typedef __attribute__((ext_vector_type(8))) short short8;
typedef __attribute__((ext_vector_type(4))) float f32x4;

__device__ __forceinline__ unsigned short f2bf(float f){
    union { float f; unsigned int i; } x; x.f = f;
    unsigned int u = x.i;
    u += 0x7fffu + ((u >> 16) & 1u);
    return (unsigned short)(u >> 16);
}
__device__ __forceinline__ unsigned int pack2(float a, float b){
    return (unsigned int)f2bf(a) | ((unsigned int)f2bf(b) << 16);
}
__device__ __forceinline__ short8 f2bf8(float4 a, float4 b){
    short8 r;
    r[0]=(short)f2bf(a.x); r[1]=(short)f2bf(a.y); r[2]=(short)f2bf(a.z); r[3]=(short)f2bf(a.w);
    r[4]=(short)f2bf(b.x); r[5]=(short)f2bf(b.y); r[6]=(short)f2bf(b.z); r[7]=(short)f2bf(b.w);
    return r;
}
__device__ __forceinline__ f32x4 mfma16(short8 a, short8 b, f32x4 c){
    return __builtin_amdgcn_mfma_f32_16x16x32_bf16(a, b, c, 0, 0, 0);
}
__device__ __forceinline__ float sigm(float x){ return 1.f / (1.f + __expf(-x)); }

// ---------------------------------------------------------------------------
// Kernel 1: x = LN(inputs); k -> k_ws[b][j][m]; v -> vT_ws[b][d][j].
// No LDS, no barriers. Grid 2048 (8 blocks/CU queued). Both tiles' x-loads
// issued up front; weights/LN params in registers for the block lifetime.
// ---------------------------------------------------------------------------
__global__ __launch_bounds__(256) void ln_kv_kernel(
    const float* __restrict__ inp,
    const float* __restrict__ g_in, const float* __restrict__ be_in,
    const float* __restrict__ Wk, const float* __restrict__ bk,
    const float* __restrict__ Wv, const float* __restrict__ bv,
    unsigned short* __restrict__ k_out, unsigned short* __restrict__ vT_out)
{
    const int t = threadIdx.x, lane = t & 63, wave = t >> 6;
    const int n16 = lane & 15, quad = lane >> 4;
    const long T0 = (long)blockIdx.x * (TPT*64);

    // x loads for all TPT tiles, issued first (deepest latency to hide)
    float4 X[TPT][4];
    #pragma unroll
    for (int c = 0; c < TPT; ++c){
        const float* rp = inp + (T0 + c*64 + wave*16 + n16) * 64;
        X[c][0] = *reinterpret_cast<const float4*>(rp + quad*8);
        X[c][1] = *reinterpret_cast<const float4*>(rp + quad*8 + 4);
        X[c][2] = *reinterpret_cast<const float4*>(rp + 32 + quad*8);
        X[c][3] = *reinterpret_cast<const float4*>(rp + 32 + quad*8 + 4);
    }

    // LN params for this lane's 16 columns
    const float4 gA = *reinterpret_cast<const float4*>(g_in + quad*8);
    const float4 gB = *reinterpret_cast<const float4*>(g_in + quad*8 + 4);
    const float4 gC = *reinterpret_cast<const float4*>(g_in + 32 + quad*8);
    const float4 gD = *reinterpret_cast<const float4*>(g_in + 32 + quad*8 + 4);
    const float4 eA = *reinterpret_cast<const float4*>(be_in + quad*8);
    const float4 eB = *reinterpret_cast<const float4*>(be_in + quad*8 + 4);
    const float4 eC = *reinterpret_cast<const float4*>(be_in + 32 + quad*8);
    const float4 eD = *reinterpret_cast<const float4*>(be_in + 32 + quad*8 + 4);

    // weight fragments (bf16), converted once per block
    short8 wka0[4], wka1[4], wvb0[4], wvb1[4];
    float4 bk4[4];
    float  bvs[4];
    #pragma unroll
    for (int mt = 0; mt < 4; ++mt){
        const float* wp = Wk + (mt*16 + n16)*64 + quad*8;
        wka0[mt] = f2bf8(*reinterpret_cast<const float4*>(wp),
                         *reinterpret_cast<const float4*>(wp + 4));
        wka1[mt] = f2bf8(*reinterpret_cast<const float4*>(wp + 32),
                         *reinterpret_cast<const float4*>(wp + 36));
        const float* vp = Wv + (mt*16 + n16)*64 + quad*8;
        wvb0[mt] = f2bf8(*reinterpret_cast<const float4*>(vp),
                         *reinterpret_cast<const float4*>(vp + 4));
        wvb1[mt] = f2bf8(*reinterpret_cast<const float4*>(vp + 32),
                         *reinterpret_cast<const float4*>(vp + 36));
        bk4[mt] = *reinterpret_cast<const float4*>(bk + mt*16 + quad*4);
        bvs[mt] = bv[mt*16 + n16];
    }

    #pragma unroll
    for (int c = 0; c < TPT; ++c){
        const long Tc = T0 + c*64;
        float4 xa = X[c][0], xb = X[c][1], xc = X[c][2], xd = X[c][3];

        float s  = (xa.x+xa.y+xa.z+xa.w) + (xb.x+xb.y+xb.z+xb.w)
                 + (xc.x+xc.y+xc.z+xc.w) + (xd.x+xd.y+xd.z+xd.w);
        float ss = (xa.x*xa.x+xa.y*xa.y+xa.z*xa.z+xa.w*xa.w)
                 + (xb.x*xb.x+xb.y*xb.y+xb.z*xb.z+xb.w*xb.w)
                 + (xc.x*xc.x+xc.y*xc.y+xc.z*xc.z+xc.w*xc.w)
                 + (xd.x*xd.x+xd.y*xd.y+xd.z*xd.z+xd.w*xd.w);
        s  += __shfl_xor(s, 16);  ss += __shfl_xor(ss, 16);
        s  += __shfl_xor(s, 32);  ss += __shfl_xor(ss, 32);
        const float mean = s * 0.015625f;
        const float rstd = rsqrtf(ss * 0.015625f - mean*mean + 1e-5f);

        float4 ya, yb, yc, yd;
        ya.x=(xa.x-mean)*rstd*gA.x+eA.x; ya.y=(xa.y-mean)*rstd*gA.y+eA.y;
        ya.z=(xa.z-mean)*rstd*gA.z+eA.z; ya.w=(xa.w-mean)*rstd*gA.w+eA.w;
        yb.x=(xb.x-mean)*rstd*gB.x+eB.x; yb.y=(xb.y-mean)*rstd*gB.y+eB.y;
        yb.z=(xb.z-mean)*rstd*gB.z+eB.z; yb.w=(xb.w-mean)*rstd*gB.w+eB.w;
        yc.x=(xc.x-mean)*rstd*gC.x+eC.x; yc.y=(xc.y-mean)*rstd*gC.y+eC.y;
        yc.z=(xc.z-mean)*rstd*gC.z+eC.z; yc.w=(xc.w-mean)*rstd*gC.w+eC.w;
        yd.x=(xd.x-mean)*rstd*gD.x+eD.x; yd.y=(xd.y-mean)*rstd*gD.y+eD.y;
        yd.z=(xd.z-mean)*rstd*gD.z+eD.z; yd.w=(xd.w-mean)*rstd*gD.w+eD.w;
        const short8 xf0 = f2bf8(ya, yb);
        const short8 xf1 = f2bf8(yc, yd);

        // k = Wk · xn^T : token Tc+wave*16+n16, feature mt*16+quad*4+r
        unsigned short* krow = k_out + (Tc + wave*16 + n16)*64;
        #pragma unroll
        for (int mt = 0; mt < 4; ++mt){
            f32x4 z = {0.f,0.f,0.f,0.f};
            z = mfma16(wka0[mt], xf0, z);
            z = mfma16(wka1[mt], xf1, z);
            uint2 pk;
            pk.x = pack2(z[0]+bk4[mt].x, z[1]+bk4[mt].y);
            pk.y = pack2(z[2]+bk4[mt].z, z[3]+bk4[mt].w);
            *reinterpret_cast<uint2*>(krow + mt*16 + quad*4) = pk;
        }
        // v = xn · Wv^T : token Tc+wave*16+quad*4+r, feature dt*16+n16
        const int bidx = (int)(Tc >> 12);
        const int jblk = ((int)Tc & 4095) + wave*16 + quad*4;
        #pragma unroll
        for (int dt = 0; dt < 4; ++dt){
            f32x4 z = {0.f,0.f,0.f,0.f};
            z = mfma16(xf0, wvb0[dt], z);
            z = mfma16(xf1, wvb1[dt], z);
            uint2 pk;
            pk.x = pack2(z[0]+bvs[dt], z[1]+bvs[dt]);
            pk.y = pack2(z[2]+bvs[dt], z[3]+bvs[dt]);
            *reinterpret_cast<uint2*>(vT_out + ((long)(bidx*64 + dt*16 + n16))*4096 + jblk) = pk;
        }
    }
}

// ---------------------------------------------------------------------------
// Kernel 2: scan — dots, softmax-over-slots, attn@V partials.
// ALL global loads (q, k, v) issued at kernel entry; the post-softmax
// update MFMAs consume registers only. attn tile is wave-private so no
// barrier between softmax-write and fragment-read (LDS in-order per wave).
// pu[b][32 seg][8 rows][80]; row 7 = vsum; col 64 = asum.
// ---------------------------------------------------------------------------
__global__ __launch_bounds__(256) void scan_kernel(
    const unsigned short* __restrict__ k_ws, const unsigned short* __restrict__ vT_ws,
    const float* __restrict__ q_ws, float* __restrict__ pu)
{
    __shared__ __align__(16) unsigned short at_all[4][16 * 40];  // per-wave [slot][32 j], pitch 40
    __shared__ float red[4][8][80];
    const int t = threadIdx.x, lane = t & 63, wave = t >> 6;
    const int n16 = lane & 15, quad = lane >> 4;
    const int b = blockIdx.x >> 5, seg = blockIdx.x & 31;
    unsigned short* at = at_all[wave];

    const int j0 = seg*128 + wave*32;      // this wave's j range (32 cols)
    const long kbase = (long)b * NN * 64;
    const long vbase = (long)b * 64 * NN;

    // ---- issue ALL global loads up front ----
    const int iq = (n16 < NSL) ? n16 : (NSL - 1);
    const float* qp = q_ws + (b*NSL + iq)*64;
    float4 q0 = *reinterpret_cast<const float4*>(qp + quad*8);
    float4 q1 = *reinterpret_cast<const float4*>(qp + quad*8 + 4);
    float4 q2 = *reinterpret_cast<const float4*>(qp + 32 + quad*8);
    float4 q3 = *reinterpret_cast<const float4*>(qp + 32 + quad*8 + 4);

    short8 kb0[2], kb1[2];
    #pragma unroll
    for (int tt = 0; tt < 2; ++tt){
        const unsigned short* kp = k_ws + kbase + (long)(j0 + tt*16 + n16)*64 + quad*8;
        kb0[tt] = *reinterpret_cast<const short8*>(kp);
        kb1[tt] = *reinterpret_cast<const short8*>(kp + 32);
    }
    short8 vb[4];
    #pragma unroll
    for (int t2 = 0; t2 < 4; ++t2)
        vb[t2] = *reinterpret_cast<const short8*>(
            vT_ws + vbase + (long)(t2*16 + n16)*NN + j0 + quad*8);

    // init attn rows 7..15: row 7 = ones (vsum trick) cols 0..31, rest zero
    for (int idx = lane; idx < 9 * 40; idx += 64){
        int rr = idx / 40, cc = idx - rr * 40;
        at[(7 + rr) * 40 + cc] = (rr == 0 && cc < 32) ? (unsigned short)0x3F80 : (unsigned short)0;
    }

    // q A-fragments (pre-scaled by 0.125 — exact scale, then bf16 round)
    short8 qa0 = f2bf8(make_float4(q0.x*0.125f,q0.y*0.125f,q0.z*0.125f,q0.w*0.125f),
                       make_float4(q1.x*0.125f,q1.y*0.125f,q1.z*0.125f,q1.w*0.125f));
    short8 qa1 = f2bf8(make_float4(q2.x*0.125f,q2.y*0.125f,q2.z*0.125f,q2.w*0.125f),
                       make_float4(q3.x*0.125f,q3.y*0.125f,q3.z*0.125f,q3.w*0.125f));

    // --- dots + softmax over slot axis, 2 tiles of 16 j ---
    #pragma unroll
    for (int tt = 0; tt < 2; ++tt){
        f32x4 dz = {0.f,0.f,0.f,0.f};
        dz = mfma16(qa0, kb0[tt], dz);
        dz = mfma16(qa1, kb1[tt], dz);
        // column j = tt*16+n16 holds slots i = quad*4 + reg; valid i = 0..6
        float pm;
        if (quad == 0)      pm = fmaxf(fmaxf(dz[0], dz[1]), fmaxf(dz[2], dz[3]));
        else if (quad == 1) pm = fmaxf(fmaxf(dz[0], dz[1]), dz[2]);
        else                pm = -1e30f;
        pm = fmaxf(pm, __shfl_xor(pm, 16));
        float e0=0.f, e1=0.f, e2=0.f, e3=0.f;
        if (quad == 0){ e0=__expf(dz[0]-pm); e1=__expf(dz[1]-pm); e2=__expf(dz[2]-pm); e3=__expf(dz[3]-pm); }
        else if (quad == 1){ e0=__expf(dz[0]-pm); e1=__expf(dz[1]-pm); e2=__expf(dz[2]-pm); }
        float ps = e0 + e1 + e2 + e3;
        ps += __shfl_xor(ps, 16);
        const float inv = 1.f / ps;
        if (quad == 0){
            at[0*40 + tt*16 + n16] = f2bf(e0*inv);
            at[1*40 + tt*16 + n16] = f2bf(e1*inv);
            at[2*40 + tt*16 + n16] = f2bf(e2*inv);
            at[3*40 + tt*16 + n16] = f2bf(e3*inv);
        } else if (quad == 1){
            at[4*40 + tt*16 + n16] = f2bf(e0*inv);
            at[5*40 + tt*16 + n16] = f2bf(e1*inv);
            at[6*40 + tt*16 + n16] = f2bf(e2*inv);
        }
    }
    // no barrier: at is wave-private and LDS ops are in-order within a wave

    // --- updates: A = attn (transposed via LDS, K=32), B = preloaded vb ---
    short8 aa = *reinterpret_cast<const short8*>(at + n16*40 + quad*8);
    short8 ones;
    { const short ov = (n16 == 0) ? (short)0x3F80 : (short)0;
      #pragma unroll
      for (int z = 0; z < 8; ++z) ones[z] = ov; }

    f32x4 uacc[5];
    #pragma unroll
    for (int t2 = 0; t2 < 4; ++t2){
        f32x4 z = {0.f,0.f,0.f,0.f};
        uacc[t2] = mfma16(aa, vb[t2], z);
    }
    { f32x4 z = {0.f,0.f,0.f,0.f}; uacc[4] = mfma16(aa, ones, z); }

    // --- cross-wave reduce -> one partial per block ---
    if (quad < 2){
        #pragma unroll
        for (int r = 0; r < 4; ++r){
            const int i = quad*4 + r;
            #pragma unroll
            for (int t2 = 0; t2 < 5; ++t2)
                red[wave][i][t2*16 + n16] = uacc[t2][r];
        }
    }
    __syncthreads();
    for (int idx = t; idx < 640; idx += 256){
        const int i = idx / 80, cc = idx - i*80;
        float s = red[0][i][cc] + red[1][i][cc] + red[2][i][cc] + red[3][i][cc];
        pu[((long)(b*32 + seg)*8 + i)*80 + cc] = s;
    }
}

// ---------------------------------------------------------------------------
// Kernel 3: slot update — grid 448 = 64 b x 7 slots, one block per slot row.
// mode 0: init slots from mu/sigma/noise + q.  mode 1: full update.
// ---------------------------------------------------------------------------
__device__ __forceinline__ float dot64(const float* x, const float* w){
    float acc = 0.f;
    const float4* w4 = reinterpret_cast<const float4*>(w);
    #pragma unroll
    for (int e4 = 0; e4 < 16; ++e4){
        float4 wv = w4[e4];
        acc += x[e4*4+0]*wv.x + x[e4*4+1]*wv.y + x[e4*4+2]*wv.z + x[e4*4+3]*wv.w;
    }
    return acc;
}
__device__ __forceinline__ float dot128(const float* x, const float* w){
    float acc = 0.f;
    const float4* w4 = reinterpret_cast<const float4*>(w);
    #pragma unroll
    for (int e4 = 0; e4 < 32; ++e4){
        float4 wv = w4[e4];
        acc += x[e4*4+0]*wv.x + x[e4*4+1]*wv.y + x[e4*4+2]*wv.z + x[e4*4+3]*wv.w;
    }
    return acc;
}

__global__ __launch_bounds__(256) void slot_update_kernel(
    const int mode, const int write_out,
    const float* __restrict__ pu,
    float* __restrict__ slots_ws, float* __restrict__ q_ws,
    const float* __restrict__ noise, const float* __restrict__ mu,
    const float* __restrict__ sigma,
    const float* __restrict__ W_ih, const float* __restrict__ W_hh,
    const float* __restrict__ b_ih, const float* __restrict__ b_hh,
    const float* __restrict__ W1, const float* __restrict__ b1,
    const float* __restrict__ W2, const float* __restrict__ b2,
    const float* __restrict__ g_sl, const float* __restrict__ be_sl,
    const float* __restrict__ g_ff, const float* __restrict__ be_ff,
    const float* __restrict__ Wq, const float* __restrict__ bq,
    float* __restrict__ out)
{
    __shared__ float hprev[64], updv[64], snew[64], ffb[64], h1[128], sfin[64], s2[64];
    __shared__ float redp[4][64], redp7[4][64];
    __shared__ float gi[192], gh[192];
    __shared__ float redA_s;
    const int t = threadIdx.x;
    const int b = blockIdx.x / NSL, i = blockIdx.x % NSL;
    const int lane = t & 63, wave = t >> 6;
    const long rowoff = (long)(b*NSL + i)*64;

    if (mode == 0){
        if (t < 64){
            float v = mu[t] + sigma[t] * noise[rowoff + t];
            sfin[t] = v;
            slots_ws[rowoff + t] = v;
        }
    } else {
        if (t < 64) hprev[t] = slots_ws[rowoff + t];
        {   // partial reduce of pu over 32 segs: 4 groups x 8 segs
            const int d = t & 63, g = t >> 6;
            float si = 0.f, s7 = 0.f;
            #pragma unroll
            for (int u = 0; u < 8; ++u){
                const float* base = pu + ((long)(b*32 + g*8 + u)*8)*80;
                si += base[i*80 + d];
                s7 += base[7*80 + d];
            }
            redp[g][d] = si; redp7[g][d] = s7;
        }
        if (wave == 0){
            float a = (lane < 32) ? pu[((long)(b*32 + lane)*8 + i)*80 + 64] : 0.f;
            #pragma unroll
            for (int m = 1; m < 64; m <<= 1) a += __shfl_xor(a, m);
            if (lane == 0) redA_s = a;
        }
        __syncthreads();
        if (t < 64){
            float ri = redp[0][t] + redp[1][t] + redp[2][t] + redp[3][t];
            float r7 = redp7[0][t] + redp7[1][t] + redp7[2][t] + redp7[3][t];
            // updates = (num + EPS*vsum) / (asum + N*EPS)  (exact reference algebra)
            updv[t] = (ri + 1e-8f * r7) / (redA_s + 4.096e-5f);
        }
        __syncthreads();
        for (int c = t; c < 384; c += 256){
            if (c < 192) gi[c] = b_ih[c] + dot64(updv, W_ih + c*64);
            else { int cc = c - 192; gh[cc] = b_hh[cc] + dot64(hprev, W_hh + cc*64); }
        }
        __syncthreads();
        if (t < 64){
            float rg = sigm(gi[t] + gh[t]);
            float zg = sigm(gi[64+t] + gh[64+t]);
            float ng = tanhf(gi[128+t] + rg * gh[128+t]);
            snew[t] = (1.f - zg) * ng + zg * hprev[t];
        }
        __syncthreads();
        {   // LN_ff (wave-redundant stats; wave 0 writes)
            float x = snew[lane];
            float s = x, ss = x * x;
            #pragma unroll
            for (int m = 1; m < 64; m <<= 1){ s += __shfl_xor(s, m); ss += __shfl_xor(ss, m); }
            float mean = s * 0.015625f;
            float var  = ss * 0.015625f - mean * mean;
            float rstd = rsqrtf(var + 1e-5f);
            if (wave == 0) ffb[lane] = (x - mean) * rstd * g_ff[lane] + be_ff[lane];
        }
        __syncthreads();
        if (t < 128){
            float vv = b1[t] + dot64(ffb, W1 + t*64);
            h1[t] = vv > 0.f ? vv : 0.f;
        }
        __syncthreads();
        if (t < 64){
            float o = b2[t] + dot128(h1, W2 + t*128);
            float v = snew[t] + o;
            sfin[t] = v;
            slots_ws[rowoff + t] = v;
            if (write_out) out[rowoff + t] = v;
        }
    }
    __syncthreads();
    {   // LN_sl for next-iteration q (wave-redundant stats; wave 0 writes)
        float x = sfin[lane];
        float s = x, ss = x * x;
        #pragma unroll
        for (int m = 1; m < 64; m <<= 1){ s += __shfl_xor(s, m); ss += __shfl_xor(ss, m); }
        float mean = s * 0.015625f;
        float var  = ss * 0.015625f - mean * mean;
        float rstd = rsqrtf(var + 1e-5f);
        if (wave == 0) s2[lane] = (x - mean) * rstd * g_sl[lane] + be_sl[lane];
    }
    __syncthreads();
    if (t < 64) q_ws[rowoff + t] = bq[t] + dot64(s2, Wq + t*64);
}

// ---------------------------------------------------------------------------
extern "C" void kernel_launch(void* const* d_in, const int* in_sizes, int n_in,
                              void* d_out, int out_size, void* d_ws, size_t ws_size,
                              hipStream_t stream)
{
    const float* inp   = (const float*)d_in[0];
    // d_in[1] = positional_embeddings: unused by the reference
    const float* noise = (const float*)d_in[2];
    const float* mu    = (const float*)d_in[3];
    const float* sigma = (const float*)d_in[4];
    const float* Wq    = (const float*)d_in[5];
    const float* bq    = (const float*)d_in[6];
    const float* Wk    = (const float*)d_in[7];
    const float* bk    = (const float*)d_in[8];
    const float* Wv    = (const float*)d_in[9];
    const float* bv    = (const float*)d_in[10];
    const float* W_ih  = (const float*)d_in[11];
    const float* W_hh  = (const float*)d_in[12];
    const float* b_ih  = (const float*)d_in[13];
    const float* b_hh  = (const float*)d_in[14];
    const float* W1    = (const float*)d_in[15];
    const float* b1    = (const float*)d_in[16];
    const float* W2    = (const float*)d_in[17];
    const float* b2    = (const float*)d_in[18];
    const float* g_in  = (const float*)d_in[19];
    const float* be_in = (const float*)d_in[20];
    const float* g_sl  = (const float*)d_in[21];
    const float* be_sl = (const float*)d_in[22];
    const float* g_ff  = (const float*)d_in[23];
    const float* be_ff = (const float*)d_in[24];
    float* out = (float*)d_out;

    char* w = (char*)d_ws;
    unsigned short* k_ws  = (unsigned short*)(w);                       // 33,554,432 B
    unsigned short* vT_ws = (unsigned short*)(w + 33554432);            // 33,554,432 B
    float* slots_ws       = (float*)(w + 67108864);                     //    114,688 B
    float* q_ws           = (float*)(w + 67108864 + 114688);            //    114,688 B
    float* pu             = (float*)(w + 67108864 + 229376);            //  5,242,880 B

    ln_kv_kernel<<<4096/TPT, 256, 0, stream>>>(inp, g_in, be_in, Wk, bk, Wv, bv, k_ws, vT_ws);
    slot_update_kernel<<<448, 256, 0, stream>>>(0, 0, pu, slots_ws, q_ws, noise, mu, sigma,
        W_ih, W_hh, b_ih, b_hh, W1, b1, W2, b2, g_sl, be_sl, g_ff, be_ff, Wq, bq, out);
    for (int it = 0; it < NITER; ++it){
        scan_kernel<<<2048, 256, 0, stream>>>(k_ws, vT_ws, q_ws, pu);
        slot_update_kernel<<<448, 256, 0, stream>>>(1, (it == NITER - 1) ? 1 : 0,
            pu, slots_ws, q_ws, noise, mu, sigma,
            W_ih, W_hh, b_ih, b_hh, W1, b1, W2, b2, g_sl, be_sl, g_ff, be_ff, Wq, bq, out);
    }
}

// Round 6
// 259.875 us; speedup vs baseline: 1.0469x; 1.0469x over previous
//
#include <hip/hip_runtime.h>
#include <stdint.h>

#define BB 64
#define NN 4096
#define DD 64
#define NSL 7
#define HH 128
#define NITER 3
#define TPT 4    // tiles (of 64 rows) per block in ln_kv
#define NSEG 16  // pu segments per batch

typedef __attribute__((ext_vector_type(8))) short short8;
typedef __attribute__((ext_vector_type(4))) float f32x4;

__device__ __forceinline__ unsigned short f2bf(float f){
    union { float f; unsigned int i; } x; x.f = f;
    unsigned int u = x.i;
    u += 0x7fffu + ((u >> 16) & 1u);
    return (unsigned short)(u >> 16);
}
__device__ __forceinline__ unsigned int pack2(float a, float b){
    return (unsigned int)f2bf(a) | ((unsigned int)f2bf(b) << 16);
}
__device__ __forceinline__ short8 f2bf8(float4 a, float4 b){
    short8 r;
    r[0]=(short)f2bf(a.x); r[1]=(short)f2bf(a.y); r[2]=(short)f2bf(a.z); r[3]=(short)f2bf(a.w);
    r[4]=(short)f2bf(b.x); r[5]=(short)f2bf(b.y); r[6]=(short)f2bf(b.z); r[7]=(short)f2bf(b.w);
    return r;
}
__device__ __forceinline__ f32x4 mfma16(short8 a, short8 b, f32x4 c){
    return __builtin_amdgcn_mfma_f32_16x16x32_bf16(a, b, c, 0, 0, 0);
}
__device__ __forceinline__ float sigm(float x){ return 1.f / (1.f + __expf(-x)); }

// ---------------------------------------------------------------------------
// Kernel 1: x = LN(inputs); k -> k_ws[b][j][m]; v -> vT_ws[b][d][j].
// No LDS/barriers. Grid 1024, TPT=4, register prefetch pipeline: next tile's
// x-loads are issued BEFORE current tile's math+stores, so the next vmcnt
// wait does not drain this tile's store queue (vmcnt FIFO counts both).
// ---------------------------------------------------------------------------
__global__ __launch_bounds__(256) void ln_kv_kernel(
    const float* __restrict__ inp,
    const float* __restrict__ g_in, const float* __restrict__ be_in,
    const float* __restrict__ Wk, const float* __restrict__ bk,
    const float* __restrict__ Wv, const float* __restrict__ bv,
    unsigned short* __restrict__ k_out, unsigned short* __restrict__ vT_out)
{
    const int t = threadIdx.x, lane = t & 63, wave = t >> 6;
    const int n16 = lane & 15, quad = lane >> 4;
    const long T0 = (long)blockIdx.x * (TPT*64);

    // first tile's x-loads, issued before anything else
    float4 Xc0, Xc1, Xc2, Xc3;
    {
        const float* rp = inp + (T0 + wave*16 + n16) * 64;
        Xc0 = *reinterpret_cast<const float4*>(rp + quad*8);
        Xc1 = *reinterpret_cast<const float4*>(rp + quad*8 + 4);
        Xc2 = *reinterpret_cast<const float4*>(rp + 32 + quad*8);
        Xc3 = *reinterpret_cast<const float4*>(rp + 32 + quad*8 + 4);
    }

    // LN params for this lane's 16 columns
    const float4 gA = *reinterpret_cast<const float4*>(g_in + quad*8);
    const float4 gB = *reinterpret_cast<const float4*>(g_in + quad*8 + 4);
    const float4 gC = *reinterpret_cast<const float4*>(g_in + 32 + quad*8);
    const float4 gD = *reinterpret_cast<const float4*>(g_in + 32 + quad*8 + 4);
    const float4 eA = *reinterpret_cast<const float4*>(be_in + quad*8);
    const float4 eB = *reinterpret_cast<const float4*>(be_in + quad*8 + 4);
    const float4 eC = *reinterpret_cast<const float4*>(be_in + 32 + quad*8);
    const float4 eD = *reinterpret_cast<const float4*>(be_in + 32 + quad*8 + 4);

    // weight fragments (bf16), converted once per block
    short8 wka0[4], wka1[4], wvb0[4], wvb1[4];
    float4 bk4[4];
    float  bvs[4];
    #pragma unroll
    for (int mt = 0; mt < 4; ++mt){
        const float* wp = Wk + (mt*16 + n16)*64 + quad*8;
        wka0[mt] = f2bf8(*reinterpret_cast<const float4*>(wp),
                         *reinterpret_cast<const float4*>(wp + 4));
        wka1[mt] = f2bf8(*reinterpret_cast<const float4*>(wp + 32),
                         *reinterpret_cast<const float4*>(wp + 36));
        const float* vp = Wv + (mt*16 + n16)*64 + quad*8;
        wvb0[mt] = f2bf8(*reinterpret_cast<const float4*>(vp),
                         *reinterpret_cast<const float4*>(vp + 4));
        wvb1[mt] = f2bf8(*reinterpret_cast<const float4*>(vp + 32),
                         *reinterpret_cast<const float4*>(vp + 36));
        bk4[mt] = *reinterpret_cast<const float4*>(bk + mt*16 + quad*4);
        bvs[mt] = bv[mt*16 + n16];
    }

    #pragma unroll
    for (int c = 0; c < TPT; ++c){
        // prefetch next tile BEFORE this tile's math/stores
        float4 Xn0, Xn1, Xn2, Xn3;
        if (c + 1 < TPT){
            const float* rp = inp + (T0 + (c+1)*64 + wave*16 + n16) * 64;
            Xn0 = *reinterpret_cast<const float4*>(rp + quad*8);
            Xn1 = *reinterpret_cast<const float4*>(rp + quad*8 + 4);
            Xn2 = *reinterpret_cast<const float4*>(rp + 32 + quad*8);
            Xn3 = *reinterpret_cast<const float4*>(rp + 32 + quad*8 + 4);
        }
        const long Tc = T0 + c*64;
        float4 xa = Xc0, xb = Xc1, xc = Xc2, xd = Xc3;

        float s  = (xa.x+xa.y+xa.z+xa.w) + (xb.x+xb.y+xb.z+xb.w)
                 + (xc.x+xc.y+xc.z+xc.w) + (xd.x+xd.y+xd.z+xd.w);
        float ss = (xa.x*xa.x+xa.y*xa.y+xa.z*xa.z+xa.w*xa.w)
                 + (xb.x*xb.x+xb.y*xb.y+xb.z*xb.z+xb.w*xb.w)
                 + (xc.x*xc.x+xc.y*xc.y+xc.z*xc.z+xc.w*xc.w)
                 + (xd.x*xd.x+xd.y*xd.y+xd.z*xd.z+xd.w*xd.w);
        s  += __shfl_xor(s, 16);  ss += __shfl_xor(ss, 16);
        s  += __shfl_xor(s, 32);  ss += __shfl_xor(ss, 32);
        const float mean = s * 0.015625f;
        const float rstd = rsqrtf(ss * 0.015625f - mean*mean + 1e-5f);

        float4 ya, yb, yc, yd;
        ya.x=(xa.x-mean)*rstd*gA.x+eA.x; ya.y=(xa.y-mean)*rstd*gA.y+eA.y;
        ya.z=(xa.z-mean)*rstd*gA.z+eA.z; ya.w=(xa.w-mean)*rstd*gA.w+eA.w;
        yb.x=(xb.x-mean)*rstd*gB.x+eB.x; yb.y=(xb.y-mean)*rstd*gB.y+eB.y;
        yb.z=(xb.z-mean)*rstd*gB.z+eB.z; yb.w=(xb.w-mean)*rstd*gB.w+eB.w;
        yc.x=(xc.x-mean)*rstd*gC.x+eC.x; yc.y=(xc.y-mean)*rstd*gC.y+eC.y;
        yc.z=(xc.z-mean)*rstd*gC.z+eC.z; yc.w=(xc.w-mean)*rstd*gC.w+eC.w;
        yd.x=(xd.x-mean)*rstd*gD.x+eD.x; yd.y=(xd.y-mean)*rstd*gD.y+eD.y;
        yd.z=(xd.z-mean)*rstd*gD.z+eD.z; yd.w=(xd.w-mean)*rstd*gD.w+eD.w;
        const short8 xf0 = f2bf8(ya, yb);
        const short8 xf1 = f2bf8(yc, yd);

        // k = Wk · xn^T : token Tc+wave*16+n16, feature mt*16+quad*4+r
        unsigned short* krow = k_out + (Tc + wave*16 + n16)*64;
        #pragma unroll
        for (int mt = 0; mt < 4; ++mt){
            f32x4 z = {0.f,0.f,0.f,0.f};
            z = mfma16(wka0[mt], xf0, z);
            z = mfma16(wka1[mt], xf1, z);
            uint2 pk;
            pk.x = pack2(z[0]+bk4[mt].x, z[1]+bk4[mt].y);
            pk.y = pack2(z[2]+bk4[mt].z, z[3]+bk4[mt].w);
            *reinterpret_cast<uint2*>(krow + mt*16 + quad*4) = pk;
        }
        // v = xn · Wv^T : token Tc+wave*16+quad*4+r, feature dt*16+n16
        const int bidx = (int)(Tc >> 12);
        const int jblk = ((int)Tc & 4095) + wave*16 + quad*4;
        #pragma unroll
        for (int dt = 0; dt < 4; ++dt){
            f32x4 z = {0.f,0.f,0.f,0.f};
            z = mfma16(xf0, wvb0[dt], z);
            z = mfma16(xf1, wvb1[dt], z);
            uint2 pk;
            pk.x = pack2(z[0]+bvs[dt], z[1]+bvs[dt]);
            pk.y = pack2(z[2]+bvs[dt], z[3]+bvs[dt]);
            *reinterpret_cast<uint2*>(vT_out + ((long)(bidx*64 + dt*16 + n16))*4096 + jblk) = pk;
        }
        Xc0 = Xn0; Xc1 = Xn1; Xc2 = Xn2; Xc3 = Xn3;
    }
}

// ---------------------------------------------------------------------------
// Kernel 2: scan — dots, softmax-over-slots, attn@V partials.
// Each wave owns 64 j; ALL ~20 global loads issued at kernel entry (max
// bytes in flight). Grid 64 b x 16 seg. attn tile wave-private (no barrier
// between softmax-write and A-frag read). pu[b][16 seg][8 rows][80];
// row 7 = vsum; col 64 = asum.
// ---------------------------------------------------------------------------
__global__ __launch_bounds__(256) void scan_kernel(
    const unsigned short* __restrict__ k_ws, const unsigned short* __restrict__ vT_ws,
    const float* __restrict__ q_ws, float* __restrict__ pu)
{
    __shared__ __align__(16) unsigned short at_all[4][16 * 72];  // per-wave [slot][64 j], pitch 72
    __shared__ float red[4][8][80];
    const int t = threadIdx.x, lane = t & 63, wave = t >> 6;
    const int n16 = lane & 15, quad = lane >> 4;
    const int b = blockIdx.x >> 4, seg = blockIdx.x & 15;
    unsigned short* at = at_all[wave];

    const int j0 = seg*256 + wave*64;      // this wave's j range (64 cols)
    const long kbase = (long)b * NN * 64;
    const long vbase = (long)b * 64 * NN;

    // ---- issue ALL global loads up front ----
    const int iq = (n16 < NSL) ? n16 : (NSL - 1);
    const float* qp = q_ws + (b*NSL + iq)*64;
    float4 q0 = *reinterpret_cast<const float4*>(qp + quad*8);
    float4 q1 = *reinterpret_cast<const float4*>(qp + quad*8 + 4);
    float4 q2 = *reinterpret_cast<const float4*>(qp + 32 + quad*8);
    float4 q3 = *reinterpret_cast<const float4*>(qp + 32 + quad*8 + 4);

    short8 kb0[4], kb1[4];
    #pragma unroll
    for (int tt = 0; tt < 4; ++tt){
        const unsigned short* kp = k_ws + kbase + (long)(j0 + tt*16 + n16)*64 + quad*8;
        kb0[tt] = *reinterpret_cast<const short8*>(kp);
        kb1[tt] = *reinterpret_cast<const short8*>(kp + 32);
    }
    short8 vba[4], vbb[4];
    #pragma unroll
    for (int t2 = 0; t2 < 4; ++t2){
        const unsigned short* vp = vT_ws + vbase + (long)(t2*16 + n16)*NN + j0 + quad*8;
        vba[t2] = *reinterpret_cast<const short8*>(vp);
        vbb[t2] = *reinterpret_cast<const short8*>(vp + 32);
    }

    // init attn rows 7..15: row 7 = ones (vsum trick) cols 0..63, rest zero
    for (int idx = lane; idx < 9 * 72; idx += 64){
        int rr = idx / 72, cc = idx - rr * 72;
        at[(7 + rr) * 72 + cc] = (rr == 0 && cc < 64) ? (unsigned short)0x3F80 : (unsigned short)0;
    }

    // q A-fragments (pre-scaled by 0.125 — exact scale, then bf16 round)
    short8 qa0 = f2bf8(make_float4(q0.x*0.125f,q0.y*0.125f,q0.z*0.125f,q0.w*0.125f),
                       make_float4(q1.x*0.125f,q1.y*0.125f,q1.z*0.125f,q1.w*0.125f));
    short8 qa1 = f2bf8(make_float4(q2.x*0.125f,q2.y*0.125f,q2.z*0.125f,q2.w*0.125f),
                       make_float4(q3.x*0.125f,q3.y*0.125f,q3.z*0.125f,q3.w*0.125f));

    // --- dots + softmax over slot axis, 4 tiles of 16 j ---
    #pragma unroll
    for (int tt = 0; tt < 4; ++tt){
        f32x4 dz = {0.f,0.f,0.f,0.f};
        dz = mfma16(qa0, kb0[tt], dz);
        dz = mfma16(qa1, kb1[tt], dz);
        // column j = tt*16+n16 holds slots i = quad*4 + reg; valid i = 0..6
        float pm;
        if (quad == 0)      pm = fmaxf(fmaxf(dz[0], dz[1]), fmaxf(dz[2], dz[3]));
        else if (quad == 1) pm = fmaxf(fmaxf(dz[0], dz[1]), dz[2]);
        else                pm = -1e30f;
        pm = fmaxf(pm, __shfl_xor(pm, 16));
        float e0=0.f, e1=0.f, e2=0.f, e3=0.f;
        if (quad == 0){ e0=__expf(dz[0]-pm); e1=__expf(dz[1]-pm); e2=__expf(dz[2]-pm); e3=__expf(dz[3]-pm); }
        else if (quad == 1){ e0=__expf(dz[0]-pm); e1=__expf(dz[1]-pm); e2=__expf(dz[2]-pm); }
        float ps = e0 + e1 + e2 + e3;
        ps += __shfl_xor(ps, 16);
        const float inv = 1.f / ps;
        if (quad == 0){
            at[0*72 + tt*16 + n16] = f2bf(e0*inv);
            at[1*72 + tt*16 + n16] = f2bf(e1*inv);
            at[2*72 + tt*16 + n16] = f2bf(e2*inv);
            at[3*72 + tt*16 + n16] = f2bf(e3*inv);
        } else if (quad == 1){
            at[4*72 + tt*16 + n16] = f2bf(e0*inv);
            at[5*72 + tt*16 + n16] = f2bf(e1*inv);
            at[6*72 + tt*16 + n16] = f2bf(e2*inv);
        }
    }
    // no barrier: at is wave-private and LDS ops are in-order within a wave

    // --- updates: A = attn (transposed via LDS, 2 K=32 chunks), B preloaded ---
    short8 aa0 = *reinterpret_cast<const short8*>(at + n16*72 + quad*8);
    short8 aa1 = *reinterpret_cast<const short8*>(at + n16*72 + 32 + quad*8);
    short8 ones;
    { const short ov = (n16 == 0) ? (short)0x3F80 : (short)0;
      #pragma unroll
      for (int z = 0; z < 8; ++z) ones[z] = ov; }

    f32x4 uacc[5];
    #pragma unroll
    for (int t2 = 0; t2 < 4; ++t2){
        f32x4 z = {0.f,0.f,0.f,0.f};
        z = mfma16(aa0, vba[t2], z);
        uacc[t2] = mfma16(aa1, vbb[t2], z);
    }
    {
        f32x4 z = {0.f,0.f,0.f,0.f};
        z = mfma16(aa0, ones, z);
        uacc[4] = mfma16(aa1, ones, z);
    }

    // --- cross-wave reduce -> one partial per block ---
    if (quad < 2){
        #pragma unroll
        for (int r = 0; r < 4; ++r){
            const int i = quad*4 + r;
            #pragma unroll
            for (int t2 = 0; t2 < 5; ++t2)
                red[wave][i][t2*16 + n16] = uacc[t2][r];
        }
    }
    __syncthreads();
    for (int idx = t; idx < 640; idx += 256){
        const int i = idx / 80, cc = idx - i*80;
        float s = red[0][i][cc] + red[1][i][cc] + red[2][i][cc] + red[3][i][cc];
        pu[((long)(b*NSEG + seg)*8 + i)*80 + cc] = s;
    }
}

// ---------------------------------------------------------------------------
// Kernel 3: slot update — grid 448 = 64 b x 7 slots, one block per slot row.
// mode 0: init slots from mu/sigma/noise + q.  mode 1: full update.
// ---------------------------------------------------------------------------
__device__ __forceinline__ float dot64(const float* x, const float* w){
    float acc = 0.f;
    const float4* w4 = reinterpret_cast<const float4*>(w);
    #pragma unroll
    for (int e4 = 0; e4 < 16; ++e4){
        float4 wv = w4[e4];
        acc += x[e4*4+0]*wv.x + x[e4*4+1]*wv.y + x[e4*4+2]*wv.z + x[e4*4+3]*wv.w;
    }
    return acc;
}
__device__ __forceinline__ float dot128(const float* x, const float* w){
    float acc = 0.f;
    const float4* w4 = reinterpret_cast<const float4*>(w);
    #pragma unroll
    for (int e4 = 0; e4 < 32; ++e4){
        float4 wv = w4[e4];
        acc += x[e4*4+0]*wv.x + x[e4*4+1]*wv.y + x[e4*4+2]*wv.z + x[e4*4+3]*wv.w;
    }
    return acc;
}

__global__ __launch_bounds__(256) void slot_update_kernel(
    const int mode, const int write_out,
    const float* __restrict__ pu,
    float* __restrict__ slots_ws, float* __restrict__ q_ws,
    const float* __restrict__ noise, const float* __restrict__ mu,
    const float* __restrict__ sigma,
    const float* __restrict__ W_ih, const float* __restrict__ W_hh,
    const float* __restrict__ b_ih, const float* __restrict__ b_hh,
    const float* __restrict__ W1, const float* __restrict__ b1,
    const float* __restrict__ W2, const float* __restrict__ b2,
    const float* __restrict__ g_sl, const float* __restrict__ be_sl,
    const float* __restrict__ g_ff, const float* __restrict__ be_ff,
    const float* __restrict__ Wq, const float* __restrict__ bq,
    float* __restrict__ out)
{
    __shared__ float hprev[64], updv[64], snew[64], ffb[64], h1[128], sfin[64], s2[64];
    __shared__ float redp[4][64], redp7[4][64];
    __shared__ float gi[192], gh[192];
    __shared__ float redA_s;
    const int t = threadIdx.x;
    const int b = blockIdx.x / NSL, i = blockIdx.x % NSL;
    const int lane = t & 63, wave = t >> 6;
    const long rowoff = (long)(b*NSL + i)*64;

    if (mode == 0){
        if (t < 64){
            float v = mu[t] + sigma[t] * noise[rowoff + t];
            sfin[t] = v;
            slots_ws[rowoff + t] = v;
        }
    } else {
        if (t < 64) hprev[t] = slots_ws[rowoff + t];
        {   // partial reduce of pu over 16 segs: 4 groups x 4 segs
            const int d = t & 63, g = t >> 6;
            float si = 0.f, s7 = 0.f;
            #pragma unroll
            for (int u = 0; u < 4; ++u){
                const float* base = pu + ((long)(b*NSEG + g*4 + u)*8)*80;
                si += base[i*80 + d];
                s7 += base[7*80 + d];
            }
            redp[g][d] = si; redp7[g][d] = s7;
        }
        if (wave == 0){
            float a = (lane < NSEG) ? pu[((long)(b*NSEG + lane)*8 + i)*80 + 64] : 0.f;
            #pragma unroll
            for (int m = 1; m < 64; m <<= 1) a += __shfl_xor(a, m);
            if (lane == 0) redA_s = a;
        }
        __syncthreads();
        if (t < 64){
            float ri = redp[0][t] + redp[1][t] + redp[2][t] + redp[3][t];
            float r7 = redp7[0][t] + redp7[1][t] + redp7[2][t] + redp7[3][t];
            // updates = (num + EPS*vsum) / (asum + N*EPS)  (exact reference algebra)
            updv[t] = (ri + 1e-8f * r7) / (redA_s + 4.096e-5f);
        }
        __syncthreads();
        for (int c = t; c < 384; c += 256){
            if (c < 192) gi[c] = b_ih[c] + dot64(updv, W_ih + c*64);
            else { int cc = c - 192; gh[cc] = b_hh[cc] + dot64(hprev, W_hh + cc*64); }
        }
        __syncthreads();
        if (t < 64){
            float rg = sigm(gi[t] + gh[t]);
            float zg = sigm(gi[64+t] + gh[64+t]);
            float ng = tanhf(gi[128+t] + rg * gh[128+t]);
            snew[t] = (1.f - zg) * ng + zg * hprev[t];
        }
        __syncthreads();
        {   // LN_ff (wave-redundant stats; wave 0 writes)
            float x = snew[lane];
            float s = x, ss = x * x;
            #pragma unroll
            for (int m = 1; m < 64; m <<= 1){ s += __shfl_xor(s, m); ss += __shfl_xor(ss, m); }
            float mean = s * 0.015625f;
            float var  = ss * 0.015625f - mean * mean;
            float rstd = rsqrtf(var + 1e-5f);
            if (wave == 0) ffb[lane] = (x - mean) * rstd * g_ff[lane] + be_ff[lane];
        }
        __syncthreads();
        if (t < 128){
            float vv = b1[t] + dot64(ffb, W1 + t*64);
            h1[t] = vv > 0.f ? vv : 0.f;
        }
        __syncthreads();
        if (t < 64){
            float o = b2[t] + dot128(h1, W2 + t*128);
            float v = snew[t] + o;
            sfin[t] = v;
            slots_ws[rowoff + t] = v;
            if (write_out) out[rowoff + t] = v;
        }
    }
    __syncthreads();
    {   // LN_sl for next-iteration q (wave-redundant stats; wave 0 writes)
        float x = sfin[lane];
        float s = x, ss = x * x;
        #pragma unroll
        for (int m = 1; m < 64; m <<= 1){ s += __shfl_xor(s, m); ss += __shfl_xor(ss, m); }
        float mean = s * 0.015625f;
        float var  = ss * 0.015625f - mean * mean;
        float rstd = rsqrtf(var + 1e-5f);
        if (wave == 0) s2[lane] = (x - mean) * rstd * g_sl[lane] + be_sl[lane];
    }
    __syncthreads();
    if (t < 64) q_ws[rowoff + t] = bq[t] + dot64(s2, Wq + t*64);
}

// ---------------------------------------------------------------------------
extern "C" void kernel_launch(void* const* d_in, const int* in_sizes, int n_in,
                              void* d_out, int out_size, void* d_ws, size_t ws_size,
                              hipStream_t stream)
{
    const float* inp   = (const float*)d_in[0];
    // d_in[1] = positional_embeddings: unused by the reference
    const float* noise = (const float*)d_in[2];
    const float* mu    = (const float*)d_in[3];
    const float* sigma = (const float*)d_in[4];
    const float* Wq    = (const float*)d_in[5];
    const float* bq    = (const float*)d_in[6];
    const float* Wk    = (const float*)d_in[7];
    const float* bk    = (const float*)d_in[8];
    const float* Wv    = (const float*)d_in[9];
    const float* bv    = (const float*)d_in[10];
    const float* W_ih  = (const float*)d_in[11];
    const float* W_hh  = (const float*)d_in[12];
    const float* b_ih  = (const float*)d_in[13];
    const float* b_hh  = (const float*)d_in[14];
    const float* W1    = (const float*)d_in[15];
    const float* b1    = (const float*)d_in[16];
    const float* W2    = (const float*)d_in[17];
    const float* b2    = (const float*)d_in[18];
    const float* g_in  = (const float*)d_in[19];
    const float* be_in = (const float*)d_in[20];
    const float* g_sl  = (const float*)d_in[21];
    const float* be_sl = (const float*)d_in[22];
    const float* g_ff  = (const float*)d_in[23];
    const float* be_ff = (const float*)d_in[24];
    float* out = (float*)d_out;

    char* w = (char*)d_ws;
    unsigned short* k_ws  = (unsigned short*)(w);                       // 33,554,432 B
    unsigned short* vT_ws = (unsigned short*)(w + 33554432);            // 33,554,432 B
    float* slots_ws       = (float*)(w + 67108864);                     //    114,688 B
    float* q_ws           = (float*)(w + 67108864 + 114688);            //    114,688 B
    float* pu             = (float*)(w + 67108864 + 229376);            //  5,242,880 B

    ln_kv_kernel<<<4096/TPT, 256, 0, stream>>>(inp, g_in, be_in, Wk, bk, Wv, bv, k_ws, vT_ws);
    slot_update_kernel<<<448, 256, 0, stream>>>(0, 0, pu, slots_ws, q_ws, noise, mu, sigma,
        W_ih, W_hh, b_ih, b_hh, W1, b1, W2, b2, g_sl, be_sl, g_ff, be_ff, Wq, bq, out);
    for (int it = 0; it < NITER; ++it){
        scan_kernel<<<64*NSEG, 256, 0, stream>>>(k_ws, vT_ws, q_ws, pu);
        slot_update_kernel<<<448, 256, 0, stream>>>(1, (it == NITER - 1) ? 1 : 0,
            pu, slots_ws, q_ws, noise, mu, sigma,
            W_ih, W_hh, b_ih, b_hh, W1, b1, W2, b2, g_sl, be_sl, g_ff, be_ff, Wq, bq, out);
    }
}